// Round 1
// baseline (202.552 us; speedup 1.0000x reference)
//
#include <hip/hip_runtime.h>

typedef _Float16 f16;
typedef _Float16 f16x8 __attribute__((ext_vector_type(8)));
typedef _Float16 f16x4 __attribute__((ext_vector_type(4)));
typedef __fp16 h16x2 __attribute__((ext_vector_type(2)));
typedef float f32x4 __attribute__((ext_vector_type(4)));

#define MFMA32(a, b, c) __builtin_amdgcn_mfma_f32_16x16x32_f16((a), (b), (c), 0, 0, 0)

static constexpr int Bb = 2, T = 2048, H = 1024, NH = 16, HD = 64;
static constexpr int M = Bb * T;      // 4096 rows
static constexpr int NQK = 2 * H;     // QK buffer row stride (Q | K)
// fold 1/sqrt(64) * log2(e) into Wq/bq so P = 2^S via raw v_exp_f32
#define QSCALE 0.1803368801111f

__device__ __forceinline__ void gload_lds16(const void* g, void* l) {
  __builtin_amdgcn_global_load_lds(
      (const __attribute__((address_space(1))) void*)g,
      (__attribute__((address_space(3))) void*)l, 16, 0, 0);
}

// ---------- fused pack kernel ----------
__global__ __launch_bounds__(256) void pack_all(const float* __restrict__ x,
                                                const float* __restrict__ Wq,
                                                const float* __restrict__ Wk,
                                                const float* __restrict__ Wv,
                                                const float* __restrict__ Wo,
                                                const float* __restrict__ bq,
                                                const float* __restrict__ bk,
                                                const float* __restrict__ bv,
                                                const int* __restrict__ mask,
                                                f16* __restrict__ xh,
                                                f16* __restrict__ WqkvT,
                                                f16* __restrict__ WoT,
                                                float* __restrict__ bqkv,
                                                float* __restrict__ maskf) {
  __shared__ f16 tile[64][65];
  const int bid = blockIdx.x;
  if (bid < 4096) {
    int i = bid * 256 + threadIdx.x;
    float4 v = ((const float4*)x)[i];
    f16x4 o;
    o[0] = (f16)v.x; o[1] = (f16)v.y; o[2] = (f16)v.z; o[3] = (f16)v.w;
    *(f16x4*)(xh + (size_t)i * 4) = o;
  } else if (bid < 5120) {
    int t = bid - 4096;
    int z = t >> 8, rem = t & 255;
    const float* W = (z == 0) ? Wq : (z == 1) ? Wk : (z == 2) ? Wv : Wo;
    f16* Wt = (z < 3) ? (WqkvT + (size_t)z * H * H) : WoT;
    const float scale = (z == 0) ? QSCALE : 1.0f;
    int k0 = (rem >> 4) * 64, n0 = (rem & 15) * 64;
    for (int p = 0; p < 16; ++p) {
      int idx = threadIdx.x + p * 256;
      int r = idx >> 6, c = idx & 63;
      tile[r][c] = (f16)(W[(size_t)(k0 + r) * H + n0 + c] * scale);
    }
    __syncthreads();
    for (int p = 0; p < 16; ++p) {
      int idx = threadIdx.x + p * 256;
      int r = idx >> 6, c = idx & 63;
      Wt[(size_t)(n0 + r) * H + k0 + c] = tile[c][r];
    }
  } else if (bid < 5132) {
    int i = (bid - 5120) * 256 + threadIdx.x;
    if (i < 3072) {
      float v = (i < 1024) ? bq[i] * QSCALE : ((i < 2048) ? bk[i - 1024] : bv[i - 2048]);
      bqkv[i] = v;
    }
  } else {
    int i = (bid - 5132) * 256 + threadIdx.x;
    if (i < Bb * T) maskf[i] = mask[i] ? 1.0f : 0.0f;
  }
}

// LDS rows of 64 f16 = 8 granules; slot s of row r holds granule s^(r&7).
__device__ __forceinline__ f16x8 lds_frag(const f16* base, int row, int gr) {
  return *(const f16x8*)(base + row * 64 + ((gr ^ (row & 7)) << 3));
}

// ---------- GEMM1: [xh @ WqkvT^T + b] -> QK (n<2048) / VT transposed (n>=2048)
// TM=128, TN=64, 3 blocks/CU, ping-pong dbuf staging. V epilogue writes the
// pre-rotated transposed layout VT[b][h][d][c], c=(t&~127)|((t+8*(d&15))&127).
__global__ __launch_bounds__(256, 3) void gemm_qkv(const f16* __restrict__ A,
                                                   const f16* __restrict__ Bt,
                                                   const float* __restrict__ bias,
                                                   f16* __restrict__ QK,
                                                   f16* __restrict__ VT) {
  constexpr int TM = 128, TN = 64, Kk = 1024;
  __shared__ f16 As[2][TM * 64];
  __shared__ f16 Bs[2][TN * 64];
  const int tid = threadIdx.x;
  const int lane = tid & 63, w = tid >> 6;
  const int quad = lane >> 4, l16 = lane & 15;
  const int wm = w >> 1, wn = w & 1;
  const int m0 = blockIdx.y * TM, n0 = blockIdx.x * TN;

  f32x4 acc[4][2];
  for (int a = 0; a < 4; ++a)
    for (int b2 = 0; b2 < 2; ++b2)
      for (int r = 0; r < 4; ++r) acc[a][b2][r] = 0.f;

  auto stage = [&](int k0, int buf) {
    for (int p = 0; p < 4; ++p) {
      int slot = p * 256 + w * 64 + lane;
      int r = slot >> 3, g = (slot & 7) ^ (r & 7);
      gload_lds16(A + (size_t)(m0 + r) * Kk + k0 + g * 8,
                  (char*)&As[buf][0] + (p * 256 + w * 64) * 16);
    }
    for (int p = 0; p < 2; ++p) {
      int slot = p * 256 + w * 64 + lane;
      int r = slot >> 3, g = (slot & 7) ^ (r & 7);
      gload_lds16(Bt + (size_t)(n0 + r) * Kk + k0 + g * 8,
                  (char*)&Bs[buf][0] + (p * 256 + w * 64) * 16);
    }
  };

  stage(0, 0);
  __syncthreads();
  for (int it = 0; it < Kk / 64; ++it) {
    const int cur = it & 1;
    if (it + 1 < Kk / 64) stage((it + 1) * 64, cur ^ 1);
    for (int ks = 0; ks < 2; ++ks) {
      f16x8 af[4], bf[2];
      for (int t = 0; t < 4; ++t)
        af[t] = lds_frag(&As[cur][0], wm * 64 + t * 16 + l16, ks * 4 + quad);
      for (int t = 0; t < 2; ++t)
        bf[t] = lds_frag(&Bs[cur][0], wn * 32 + t * 16 + l16, ks * 4 + quad);
      for (int tm = 0; tm < 4; ++tm)
        for (int tn = 0; tn < 2; ++tn)
          acc[tm][tn] = MFMA32(af[tm], bf[tn], acc[tm][tn]);
    }
    __syncthreads();
  }

  if (n0 < 2048) {
    for (int tm = 0; tm < 4; ++tm)
      for (int tn = 0; tn < 2; ++tn) {
        int n = n0 + wn * 32 + tn * 16 + l16;
        float bn = bias[n];
        for (int r = 0; r < 4; ++r) {
          int m = m0 + wm * 64 + tm * 16 + quad * 4 + r;
          QK[(size_t)m * NQK + n] = (f16)(acc[tm][tn][r] + bn);
        }
      }
  } else {
    for (int tm = 0; tm < 4; ++tm)
      for (int tn = 0; tn < 2; ++tn) {
        int ng = n0 + wn * 32 + tn * 16 + l16;
        float bn = bias[ng];
        int n = ng - 2048;
        int h = n >> 6, d = n & 63;
        int mrow = m0 + wm * 64 + tm * 16 + quad * 4;
        int bb = mrow >> 11, t = mrow & 2047;
        int c = (t & ~127) | ((t + 8 * (d & 15)) & 127);
        f16x4 o;
        for (int r = 0; r < 4; ++r) o[r] = (f16)(acc[tm][tn][r] + bn);
        *(f16x4*)(VT + ((size_t)(bb * NH + h) * HD + d) * T + c) = o;
      }
  }
}

// ---------- GEMM2: out = ctx @ WoT^T + bo (f32 out) ----------
__global__ __launch_bounds__(256, 3) void gemm_out(const f16* __restrict__ A,
                                                   const f16* __restrict__ Bt,
                                                   const float* __restrict__ bias,
                                                   float* __restrict__ Cout) {
  constexpr int TM = 128, TN = 64, Kk = 1024, Nn = 1024;
  __shared__ f16 As[2][TM * 64];
  __shared__ f16 Bs[2][TN * 64];
  const int tid = threadIdx.x;
  const int lane = tid & 63, w = tid >> 6;
  const int quad = lane >> 4, l16 = lane & 15;
  const int wm = w >> 1, wn = w & 1;
  const int m0 = blockIdx.y * TM, n0 = blockIdx.x * TN;

  f32x4 acc[4][2];
  for (int a = 0; a < 4; ++a)
    for (int b2 = 0; b2 < 2; ++b2)
      for (int r = 0; r < 4; ++r) acc[a][b2][r] = 0.f;

  auto stage = [&](int k0, int buf) {
    for (int p = 0; p < 4; ++p) {
      int slot = p * 256 + w * 64 + lane;
      int r = slot >> 3, g = (slot & 7) ^ (r & 7);
      gload_lds16(A + (size_t)(m0 + r) * Kk + k0 + g * 8,
                  (char*)&As[buf][0] + (p * 256 + w * 64) * 16);
    }
    for (int p = 0; p < 2; ++p) {
      int slot = p * 256 + w * 64 + lane;
      int r = slot >> 3, g = (slot & 7) ^ (r & 7);
      gload_lds16(Bt + (size_t)(n0 + r) * Kk + k0 + g * 8,
                  (char*)&Bs[buf][0] + (p * 256 + w * 64) * 16);
    }
  };

  stage(0, 0);
  __syncthreads();
  for (int it = 0; it < Kk / 64; ++it) {
    const int cur = it & 1;
    if (it + 1 < Kk / 64) stage((it + 1) * 64, cur ^ 1);
    for (int ks = 0; ks < 2; ++ks) {
      f16x8 af[4], bf[2];
      for (int t = 0; t < 4; ++t)
        af[t] = lds_frag(&As[cur][0], wm * 64 + t * 16 + l16, ks * 4 + quad);
      for (int t = 0; t < 2; ++t)
        bf[t] = lds_frag(&Bs[cur][0], wn * 32 + t * 16 + l16, ks * 4 + quad);
      for (int tm = 0; tm < 4; ++tm)
        for (int tn = 0; tn < 2; ++tn)
          acc[tm][tn] = MFMA32(af[tm], bf[tn], acc[tm][tn]);
    }
    __syncthreads();
  }

  for (int tm = 0; tm < 4; ++tm)
    for (int tn = 0; tn < 2; ++tn) {
      int n = n0 + wn * 32 + tn * 16 + l16;
      float bn = bias[n];
      for (int r = 0; r < 4; ++r) {
        int m = m0 + wm * 64 + tm * 16 + quad * 4 + r;
        Cout[(size_t)m * Nn + n] = acc[tm][tn][r] + bn;
      }
    }
}

// ---------- flash attention v10: 128-row q-blocks, 2 blocks/CU ----------
// Block = 512 thr = 4 q-waves x 2 kv-groups; 128 q/block (tq=2); kv tile 128
// dbuf. Grid = (T/128, NH, B) = 512 blocks -> 2 blocks/CU co-resident (LDS
// 64KB), 16 waves/CU: a second block's MFMA stream covers this block's
// barrier drains and softmax VALU phases. Bijective XCD swizzle: each XCD's
// 64 blocks = 4 (b,h) pairs x 16 q-blocks -> K/V working set 2MB < 4MB L2.
// Inner per-32-kv-block computation identical to v9 (phase-split ILP).

static constexpr int KT_ELE = 128 * 64;
static constexpr int VT_ELE = 64 * 128;

__global__ __launch_bounds__(512, 4) void attn_fused(const f16* __restrict__ QK,
                                                     const f16* __restrict__ VT,
                                                     const float* __restrict__ maskf,
                                                     f16* __restrict__ ctx) {
  __shared__ __align__(16) char smem[65536];  // staging 64KB | combine 35.8KB
  f16* KtB = (f16*)smem;
  f16* VtB = (f16*)(smem + 2 * KT_ELE * 2);

  const int tid = threadIdx.x;
  const int w = tid >> 6, lane = tid & 63;
  const int quad = lane >> 4, l16 = lane & 15;
  const int qw = w & 3, g = w >> 2;

  // XCD-aware bijective swizzle (512 blocks % 8 XCDs == 0)
  const int flat = blockIdx.x + (T / 128) * (blockIdx.y + NH * blockIdx.z);
  const int xcd = flat & 7, idx = flat >> 3;         // idx 0..63 per XCD
  const int bh = xcd * 4 + (idx >> 4);               // 4 (b,h) pairs per XCD
  const int qb = idx & 15;                           // 16 q-blocks per (b,h)
  const int h = bh & 15, b = bh >> 4;
  const int q0 = qb * 128;

  const size_t kbase = (size_t)(b * T) * NQK + H + h * HD;
  const size_t vtbase = ((size_t)(b * NH + h) * HD) * T;
  const float* maskp = maskf + b * T;

  // Q B-frags (each q-wave owns 32 rows = 2 tiles of 16)
  f16x8 qf[2][2];
  for (int tq = 0; tq < 2; ++tq) {
    const f16* qrow = QK + (size_t)(b * T + q0 + qw * 32 + tq * 16 + l16) * NQK + h * HD;
    qf[tq][0] = *(const f16x8*)(qrow + quad * 8);
    qf[tq][1] = *(const f16x8*)(qrow + 32 + quad * 8);
  }

  f32x4 oacc[2][4];
  float lsum[2] = {0.f, 0.f};
  for (int tq = 0; tq < 2; ++tq)
    for (int t = 0; t < 4; ++t)
      for (int r = 0; r < 4; ++r) oacc[tq][t][r] = 0.f;

  auto stage = [&](int kv0, int buf) {
    f16* Kd = KtB + buf * KT_ELE;
    f16* Vd = VtB + buf * VT_ELE;
    for (int p = 0; p < 2; ++p) {
      int s = p * 512 + tid;
      int R = s >> 3, sg = (s & 7) ^ (R & 7);
      int kv = (R & ~31) | ((R & 12) << 1) | ((R & 16) >> 2) | (R & 3);
      gload_lds16(QK + kbase + (size_t)(kv0 + kv) * NQK + sg * 8,
                  (char*)Kd + (p * 512 + w * 64) * 16);
    }
    for (int p = 0; p < 2; ++p) {
      int s = p * 512 + tid;
      int d = s >> 4, cg = s & 15;
      gload_lds16(VT + vtbase + (size_t)d * T + kv0 + cg * 8,
                  (char*)Vd + (p * 512 + w * 64) * 16);
    }
  };

  stage(0, 0);
  __syncthreads();

  for (int it = 0; it < T / 128; ++it) {
    const int cur = it & 1;
    if (it + 1 < T / 128) stage((it + 1) * 128, cur ^ 1);

    const f16* Kc = KtB + cur * KT_ELE;
    const f16* Vc = VtB + cur * VT_ELE;

    for (int s = 0; s < 2; ++s) {
      const int bi = g * 2 + s;               // 32-kv block index in tile
      const int kvabs = it * 128 + bi * 32;
      float4 m0 = *(const float4*)(maskp + kvabs + quad * 8);
      float4 m1 = *(const float4*)(maskp + kvabs + quad * 8 + 4);
      f16x8 kfA0 = lds_frag(Kc, bi * 32 + l16, quad);
      f16x8 kfA1 = lds_frag(Kc, bi * 32 + l16, 4 + quad);
      f16x8 kfB0 = lds_frag(Kc, bi * 32 + 16 + l16, quad);
      f16x8 kfB1 = lds_frag(Kc, bi * 32 + 16 + l16, 4 + quad);
      f16x8 vf[4];
      for (int td = 0; td < 4; ++td)
        vf[td] = *(const f16x8*)&Vc[(td * 16 + l16) * 128 +
                                    ((bi * 32 + quad * 8 + 8 * l16) & 127)];

      // phase 1: all QK MFMAs (8, independent chains of 2)
      f32x4 sA[2], sB[2];
      for (int tq = 0; tq < 2; ++tq) {
        f32x4 z = {0.f, 0.f, 0.f, 0.f};
        sA[tq] = MFMA32(kfA0, qf[tq][0], z);
        sB[tq] = MFMA32(kfB0, qf[tq][0], z);
      }
      for (int tq = 0; tq < 2; ++tq) {
        sA[tq] = MFMA32(kfA1, qf[tq][1], sA[tq]);
        sB[tq] = MFMA32(kfB1, qf[tq][1], sB[tq]);
      }

      // phase 2: softmax VALU (all tq)
      f16x8 pf[2];
      for (int tq = 0; tq < 2; ++tq) {
        float pA0 = __builtin_amdgcn_exp2f(sA[tq][0]) * m0.x;
        float pA1 = __builtin_amdgcn_exp2f(sA[tq][1]) * m0.y;
        float pA2 = __builtin_amdgcn_exp2f(sA[tq][2]) * m0.z;
        float pA3 = __builtin_amdgcn_exp2f(sA[tq][3]) * m0.w;
        float pB0 = __builtin_amdgcn_exp2f(sB[tq][0]) * m1.x;
        float pB1 = __builtin_amdgcn_exp2f(sB[tq][1]) * m1.y;
        float pB2 = __builtin_amdgcn_exp2f(sB[tq][2]) * m1.z;
        float pB3 = __builtin_amdgcn_exp2f(sB[tq][3]) * m1.w;
        lsum[tq] += ((pA0 + pA1) + (pA2 + pA3)) + ((pB0 + pB1) + (pB2 + pB3));
        union PF { f16x8 v; h16x2 h[4]; } u;
        u.h[0] = __builtin_amdgcn_cvt_pkrtz(pA0, pA1);
        u.h[1] = __builtin_amdgcn_cvt_pkrtz(pA2, pA3);
        u.h[2] = __builtin_amdgcn_cvt_pkrtz(pB0, pB1);
        u.h[3] = __builtin_amdgcn_cvt_pkrtz(pB2, pB3);
        pf[tq] = u.v;
      }

      // phase 3: all PV MFMAs (8, independent accumulators)
      for (int tq = 0; tq < 2; ++tq)
        for (int td = 0; td < 4; ++td)
          oacc[tq][td] = MFMA32(vf[td], pf[tq], oacc[tq][td]);
    }
    __syncthreads();
  }

  // ---- combine the 2 kv-groups (additive partials; 34 floats, stride 35) ----
  float* cmb = (float*)smem;
  const int slot = qw * 64 + lane;
  if (g == 1) {
    float* dst = cmb + slot * 35;
    int i = 0;
    for (int tq = 0; tq < 2; ++tq)
      for (int td = 0; td < 4; ++td)
        for (int r = 0; r < 4; ++r) dst[i++] = oacc[tq][td][r];
    for (int tq = 0; tq < 2; ++tq) dst[32 + tq] = lsum[tq];
  }
  __syncthreads();
  if (g == 0) {
    const float* src = cmb + slot * 35;
    int i = 0;
    for (int tq = 0; tq < 2; ++tq)
      for (int td = 0; td < 4; ++td)
        for (int r = 0; r < 4; ++r) oacc[tq][td][r] += src[i++];
    for (int tq = 0; tq < 2; ++tq) lsum[tq] += src[32 + tq];

    for (int tq = 0; tq < 2; ++tq) {
      float l = lsum[tq];
      l += __shfl_xor(l, 16, 64);
      l += __shfl_xor(l, 32, 64);
      float inv = 1.f / l;
      int row = b * T + q0 + qw * 32 + tq * 16 + l16;
      for (int td = 0; td < 4; ++td) {
        f16x4 o;
        for (int r = 0; r < 4; ++r) o[r] = (f16)(oacc[tq][td][r] * inv);
        *(f16x4*)(ctx + (size_t)row * H + h * HD + td * 16 + quad * 4) = o;
      }
    }
  }
}

// ---------- launch ----------

extern "C" void kernel_launch(void* const* d_in, const int* in_sizes, int n_in,
                              void* d_out, int out_size, void* d_ws, size_t ws_size,
                              hipStream_t stream) {
  const float* x  = (const float*)d_in[0];
  const int* mask = (const int*)d_in[1];
  const float* Wq = (const float*)d_in[2];
  const float* bq = (const float*)d_in[3];
  const float* Wk = (const float*)d_in[4];
  const float* bk = (const float*)d_in[5];
  const float* Wv = (const float*)d_in[6];
  const float* bv = (const float*)d_in[7];
  const float* Wo = (const float*)d_in[8];
  const float* bo = (const float*)d_in[9];
  float* out = (float*)d_out;

  char* ws = (char*)d_ws;
  f16* xh      = (f16*)(ws);                            // 8 MB
  f16* Wqkv_t  = (f16*)(ws + (8u  << 20));              // 6 MB
  f16* Wot     = (f16*)(ws + (14u << 20));              // 2 MB
  float* bqkv  = (float*)(ws + (16u << 20));            // 12 KB
  float* maskf = (float*)(ws + (16u << 20) + 65536);    // 16 KB
  f16* QK      = (f16*)(ws + (17u << 20));              // 16 MB [4096][2048]
  f16* ctx     = (f16*)(ws + (34u << 20));              // 8 MB
  f16* VTr     = (f16*)(ws + (43u << 20));              // 8 MB [B][NH][64][T]

  pack_all<<<dim3(5164), 256, 0, stream>>>(x, Wq, Wk, Wv, Wo, bq, bk, bv, mask,
                                           xh, Wqkv_t, Wot, bqkv, maskf);

  gemm_qkv<<<dim3(3 * H / 64, M / 128), 256, 0, stream>>>(
      xh, Wqkv_t, bqkv, QK, VTr);

  attn_fused<<<dim3(T / 128, NH, Bb), 512, 0, stream>>>(QK, VTr, maskf, ctx);

  gemm_out<<<dim3(H / 64, M / 128), 256, 0, stream>>>(ctx, Wot, bo, out);
}

// Round 2
// 184.566 us; speedup vs baseline: 1.0975x; 1.0975x over previous
//
#include <hip/hip_runtime.h>

typedef _Float16 f16;
typedef _Float16 f16x8 __attribute__((ext_vector_type(8)));
typedef _Float16 f16x4 __attribute__((ext_vector_type(4)));
typedef __fp16 h16x2 __attribute__((ext_vector_type(2)));
typedef float f32x4 __attribute__((ext_vector_type(4)));

#define MFMA32(a, b, c) __builtin_amdgcn_mfma_f32_16x16x32_f16((a), (b), (c), 0, 0, 0)

static constexpr int Bb = 2, T = 2048, H = 1024, NH = 16, HD = 64;
static constexpr int M = Bb * T;      // 4096 rows
static constexpr int NQK = 2 * H;     // QK buffer row stride (Q | K)
// fold 1/sqrt(64) * log2(e) into Wq/bq so P = 2^S via raw v_exp_f32
#define QSCALE 0.1803368801111f

__device__ __forceinline__ void gload_lds16(const void* g, void* l) {
  __builtin_amdgcn_global_load_lds(
      (const __attribute__((address_space(1))) void*)g,
      (__attribute__((address_space(3))) void*)l, 16, 0, 0);
}

// ---------- fused pack kernel ----------
__global__ __launch_bounds__(256) void pack_all(const float* __restrict__ x,
                                                const float* __restrict__ Wq,
                                                const float* __restrict__ Wk,
                                                const float* __restrict__ Wv,
                                                const float* __restrict__ Wo,
                                                const float* __restrict__ bq,
                                                const float* __restrict__ bk,
                                                const float* __restrict__ bv,
                                                const int* __restrict__ mask,
                                                f16* __restrict__ xh,
                                                f16* __restrict__ WqkvT,
                                                f16* __restrict__ WoT,
                                                float* __restrict__ bqkv,
                                                float* __restrict__ maskf) {
  __shared__ f16 tile[64][65];
  const int bid = blockIdx.x;
  if (bid < 4096) {
    int i = bid * 256 + threadIdx.x;
    float4 v = ((const float4*)x)[i];
    f16x4 o;
    o[0] = (f16)v.x; o[1] = (f16)v.y; o[2] = (f16)v.z; o[3] = (f16)v.w;
    *(f16x4*)(xh + (size_t)i * 4) = o;
  } else if (bid < 5120) {
    int t = bid - 4096;
    int z = t >> 8, rem = t & 255;
    const float* W = (z == 0) ? Wq : (z == 1) ? Wk : (z == 2) ? Wv : Wo;
    f16* Wt = (z < 3) ? (WqkvT + (size_t)z * H * H) : WoT;
    const float scale = (z == 0) ? QSCALE : 1.0f;
    int k0 = (rem >> 4) * 64, n0 = (rem & 15) * 64;
    for (int p = 0; p < 16; ++p) {
      int idx = threadIdx.x + p * 256;
      int r = idx >> 6, c = idx & 63;
      tile[r][c] = (f16)(W[(size_t)(k0 + r) * H + n0 + c] * scale);
    }
    __syncthreads();
    for (int p = 0; p < 16; ++p) {
      int idx = threadIdx.x + p * 256;
      int r = idx >> 6, c = idx & 63;
      Wt[(size_t)(n0 + r) * H + k0 + c] = tile[c][r];
    }
  } else if (bid < 5132) {
    int i = (bid - 5120) * 256 + threadIdx.x;
    if (i < 3072) {
      float v = (i < 1024) ? bq[i] * QSCALE : ((i < 2048) ? bk[i - 1024] : bv[i - 2048]);
      bqkv[i] = v;
    }
  } else {
    int i = (bid - 5132) * 256 + threadIdx.x;
    // log2-domain mask bias: P = exp2(S + bias); 0 keeps, -3e4 kills (exp2 -> 0)
    if (i < Bb * T) maskf[i] = mask[i] ? 0.0f : -30000.0f;
  }
}

// LDS rows of 64 f16 = 8 granules; slot s of row r holds granule s^(r&7).
__device__ __forceinline__ f16x8 lds_frag(const f16* base, int row, int gr) {
  return *(const f16x8*)(base + row * 64 + ((gr ^ (row & 7)) << 3));
}

// ---------- GEMM1: [xh @ WqkvT^T + b] -> QK (n<2048) / VT transposed (n>=2048)
// TM=128, TN=64, 3 blocks/CU, ping-pong dbuf staging. V epilogue writes the
// pre-rotated transposed layout VT[b][h][d][c], c=(t&~127)|((t+8*(d&15))&127).
__global__ __launch_bounds__(256, 3) void gemm_qkv(const f16* __restrict__ A,
                                                   const f16* __restrict__ Bt,
                                                   const float* __restrict__ bias,
                                                   f16* __restrict__ QK,
                                                   f16* __restrict__ VT) {
  constexpr int TM = 128, TN = 64, Kk = 1024;
  __shared__ f16 As[2][TM * 64];
  __shared__ f16 Bs[2][TN * 64];
  const int tid = threadIdx.x;
  const int lane = tid & 63, w = tid >> 6;
  const int quad = lane >> 4, l16 = lane & 15;
  const int wm = w >> 1, wn = w & 1;
  const int m0 = blockIdx.y * TM, n0 = blockIdx.x * TN;

  f32x4 acc[4][2];
  for (int a = 0; a < 4; ++a)
    for (int b2 = 0; b2 < 2; ++b2)
      for (int r = 0; r < 4; ++r) acc[a][b2][r] = 0.f;

  auto stage = [&](int k0, int buf) {
    for (int p = 0; p < 4; ++p) {
      int slot = p * 256 + w * 64 + lane;
      int r = slot >> 3, g = (slot & 7) ^ (r & 7);
      gload_lds16(A + (size_t)(m0 + r) * Kk + k0 + g * 8,
                  (char*)&As[buf][0] + (p * 256 + w * 64) * 16);
    }
    for (int p = 0; p < 2; ++p) {
      int slot = p * 256 + w * 64 + lane;
      int r = slot >> 3, g = (slot & 7) ^ (r & 7);
      gload_lds16(Bt + (size_t)(n0 + r) * Kk + k0 + g * 8,
                  (char*)&Bs[buf][0] + (p * 256 + w * 64) * 16);
    }
  };

  stage(0, 0);
  __syncthreads();
  for (int it = 0; it < Kk / 64; ++it) {
    const int cur = it & 1;
    if (it + 1 < Kk / 64) stage((it + 1) * 64, cur ^ 1);
    for (int ks = 0; ks < 2; ++ks) {
      f16x8 af[4], bf[2];
      for (int t = 0; t < 4; ++t)
        af[t] = lds_frag(&As[cur][0], wm * 64 + t * 16 + l16, ks * 4 + quad);
      for (int t = 0; t < 2; ++t)
        bf[t] = lds_frag(&Bs[cur][0], wn * 32 + t * 16 + l16, ks * 4 + quad);
      for (int tm = 0; tm < 4; ++tm)
        for (int tn = 0; tn < 2; ++tn)
          acc[tm][tn] = MFMA32(af[tm], bf[tn], acc[tm][tn]);
    }
    __syncthreads();
  }

  if (n0 < 2048) {
    for (int tm = 0; tm < 4; ++tm)
      for (int tn = 0; tn < 2; ++tn) {
        int n = n0 + wn * 32 + tn * 16 + l16;
        float bn = bias[n];
        for (int r = 0; r < 4; ++r) {
          int m = m0 + wm * 64 + tm * 16 + quad * 4 + r;
          QK[(size_t)m * NQK + n] = (f16)(acc[tm][tn][r] + bn);
        }
      }
  } else {
    for (int tm = 0; tm < 4; ++tm)
      for (int tn = 0; tn < 2; ++tn) {
        int ng = n0 + wn * 32 + tn * 16 + l16;
        float bn = bias[ng];
        int n = ng - 2048;
        int h = n >> 6, d = n & 63;
        int mrow = m0 + wm * 64 + tm * 16 + quad * 4;
        int bb = mrow >> 11, t = mrow & 2047;
        int c = (t & ~127) | ((t + 8 * (d & 15)) & 127);
        f16x4 o;
        for (int r = 0; r < 4; ++r) o[r] = (f16)(acc[tm][tn][r] + bn);
        *(f16x4*)(VT + ((size_t)(bb * NH + h) * HD + d) * T + c) = o;
      }
  }
}

// ---------- GEMM2: out = ctx @ WoT^T + bo (f32 out) ----------
__global__ __launch_bounds__(256, 3) void gemm_out(const f16* __restrict__ A,
                                                   const f16* __restrict__ Bt,
                                                   const float* __restrict__ bias,
                                                   float* __restrict__ Cout) {
  constexpr int TM = 128, TN = 64, Kk = 1024, Nn = 1024;
  __shared__ f16 As[2][TM * 64];
  __shared__ f16 Bs[2][TN * 64];
  const int tid = threadIdx.x;
  const int lane = tid & 63, w = tid >> 6;
  const int quad = lane >> 4, l16 = lane & 15;
  const int wm = w >> 1, wn = w & 1;
  const int m0 = blockIdx.y * TM, n0 = blockIdx.x * TN;

  f32x4 acc[4][2];
  for (int a = 0; a < 4; ++a)
    for (int b2 = 0; b2 < 2; ++b2)
      for (int r = 0; r < 4; ++r) acc[a][b2][r] = 0.f;

  auto stage = [&](int k0, int buf) {
    for (int p = 0; p < 4; ++p) {
      int slot = p * 256 + w * 64 + lane;
      int r = slot >> 3, g = (slot & 7) ^ (r & 7);
      gload_lds16(A + (size_t)(m0 + r) * Kk + k0 + g * 8,
                  (char*)&As[buf][0] + (p * 256 + w * 64) * 16);
    }
    for (int p = 0; p < 2; ++p) {
      int slot = p * 256 + w * 64 + lane;
      int r = slot >> 3, g = (slot & 7) ^ (r & 7);
      gload_lds16(Bt + (size_t)(n0 + r) * Kk + k0 + g * 8,
                  (char*)&Bs[buf][0] + (p * 256 + w * 64) * 16);
    }
  };

  stage(0, 0);
  __syncthreads();
  for (int it = 0; it < Kk / 64; ++it) {
    const int cur = it & 1;
    if (it + 1 < Kk / 64) stage((it + 1) * 64, cur ^ 1);
    for (int ks = 0; ks < 2; ++ks) {
      f16x8 af[4], bf[2];
      for (int t = 0; t < 4; ++t)
        af[t] = lds_frag(&As[cur][0], wm * 64 + t * 16 + l16, ks * 4 + quad);
      for (int t = 0; t < 2; ++t)
        bf[t] = lds_frag(&Bs[cur][0], wn * 32 + t * 16 + l16, ks * 4 + quad);
      for (int tm = 0; tm < 4; ++tm)
        for (int tn = 0; tn < 2; ++tn)
          acc[tm][tn] = MFMA32(af[tm], bf[tn], acc[tm][tn]);
    }
    __syncthreads();
  }

  for (int tm = 0; tm < 4; ++tm)
    for (int tn = 0; tn < 2; ++tn) {
      int n = n0 + wn * 32 + tn * 16 + l16;
      float bn = bias[n];
      for (int r = 0; r < 4; ++r) {
        int m = m0 + wm * 64 + tm * 16 + quad * 4 + r;
        Cout[(size_t)m * Nn + n] = acc[tm][tn][r] + bn;
      }
    }
}

// ---------- flash attention v11: v9 structure + mask-as-C-bias + MFMA lsum ----------
// Block = 512 thr = 4 q-waves x 2 kv-groups; 256 q/block; kv tile 128 dbuf.
// Softmax VALU cut: mask folded into QK MFMA C-in (log2 domain, 0/-3e4) and
// row-sum computed by a ones-vector PV MFMA (full k=32 reduce in matrix pipe,
// kills the mask muls, lsum adds AND the final cross-quad shuffles).
// Bijective XCD swizzle: 256 blocks, 4 (b,h) per XCD -> 2MB K/V per L2.

static constexpr int KT_ELE = 128 * 64;
static constexpr int VT_ELE = 64 * 128;

__global__ __launch_bounds__(512, 2) void attn_fused(const f16* __restrict__ QK,
                                                     const f16* __restrict__ VT,
                                                     const float* __restrict__ maskf,
                                                     f16* __restrict__ ctx) {
  __shared__ __align__(16) char smem[70656];  // staging 64KB | combine 70.6KB
  f16* KtB = (f16*)smem;
  f16* VtB = (f16*)(smem + 2 * KT_ELE * 2);

  const int tid = threadIdx.x;
  const int w = tid >> 6, lane = tid & 63;
  const int quad = lane >> 4, l16 = lane & 15;
  const int qw = w & 3, g = w >> 2;

  // XCD-aware bijective swizzle (256 blocks % 8 XCDs == 0):
  // each XCD gets 4 (b,h) pairs x 8 q-blocks -> K/V working set 2MB < 4MB L2
  const int flat = blockIdx.x + (T / 256) * (blockIdx.y + NH * blockIdx.z);
  const int xcd = flat & 7, idx = flat >> 3;   // idx 0..31 per XCD
  const int bh = xcd * 4 + (idx >> 3);         // 4 (b,h) pairs per XCD
  const int qb = idx & 7;                      // 8 q-blocks per (b,h)
  const int h = bh & 15, b = bh >> 4;
  const int q0 = qb * 256;

  const size_t kbase = (size_t)(b * T) * NQK + H + h * HD;
  const size_t vtbase = ((size_t)(b * NH + h) * HD) * T;
  const float* maskp = maskf + b * T;

  // Q B-frags
  f16x8 qf[4][2];
  for (int tq = 0; tq < 4; ++tq) {
    const f16* qrow = QK + (size_t)(b * T + q0 + qw * 64 + tq * 16 + l16) * NQK + h * HD;
    qf[tq][0] = *(const f16x8*)(qrow + quad * 8);
    qf[tq][1] = *(const f16x8*)(qrow + 32 + quad * 8);
  }

  f16x8 onesf;
  for (int i = 0; i < 8; ++i) onesf[i] = (f16)1.0f;

  f32x4 oacc[4][4];
  f32x4 lacc[4];
  for (int tq = 0; tq < 4; ++tq) {
    for (int r = 0; r < 4; ++r) lacc[tq][r] = 0.f;
    for (int t = 0; t < 4; ++t)
      for (int r = 0; r < 4; ++r) oacc[tq][t][r] = 0.f;
  }

  auto stage = [&](int kv0, int buf) {
    f16* Kd = KtB + buf * KT_ELE;
    f16* Vd = VtB + buf * VT_ELE;
    for (int p = 0; p < 2; ++p) {
      int s = p * 512 + tid;
      int R = s >> 3, sg = (s & 7) ^ (R & 7);
      int kv = (R & ~31) | ((R & 12) << 1) | ((R & 16) >> 2) | (R & 3);
      gload_lds16(QK + kbase + (size_t)(kv0 + kv) * NQK + sg * 8,
                  (char*)Kd + (p * 512 + w * 64) * 16);
    }
    for (int p = 0; p < 2; ++p) {
      int s = p * 512 + tid;
      int d = s >> 4, cg = s & 15;
      gload_lds16(VT + vtbase + (size_t)d * T + kv0 + cg * 8,
                  (char*)Vd + (p * 512 + w * 64) * 16);
    }
  };

  stage(0, 0);
  __syncthreads();

  for (int it = 0; it < T / 128; ++it) {
    const int cur = it & 1;
    if (it + 1 < T / 128) stage((it + 1) * 128, cur ^ 1);

    const f16* Kc = KtB + cur * KT_ELE;
    const f16* Vc = VtB + cur * VT_ELE;

    for (int s = 0; s < 2; ++s) {
      const int bi = g * 2 + s;               // 32-kv block index in tile
      const int kvabs = it * 128 + bi * 32;
      float4 m0 = *(const float4*)(maskp + kvabs + quad * 8);
      float4 m1 = *(const float4*)(maskp + kvabs + quad * 8 + 4);
      f32x4 zA, zB;
      zA[0] = m0.x; zA[1] = m0.y; zA[2] = m0.z; zA[3] = m0.w;
      zB[0] = m1.x; zB[1] = m1.y; zB[2] = m1.z; zB[3] = m1.w;
      f16x8 kfA0 = lds_frag(Kc, bi * 32 + l16, quad);
      f16x8 kfA1 = lds_frag(Kc, bi * 32 + l16, 4 + quad);
      f16x8 kfB0 = lds_frag(Kc, bi * 32 + 16 + l16, quad);
      f16x8 kfB1 = lds_frag(Kc, bi * 32 + 16 + l16, 4 + quad);
      f16x8 vf[4];
      for (int td = 0; td < 4; ++td)
        vf[td] = *(const f16x8*)&Vc[(td * 16 + l16) * 128 +
                                    ((bi * 32 + quad * 8 + 8 * l16) & 127)];

      // phase 1: all QK MFMAs (16, independent chains of 2); mask bias as C-in
      f32x4 sA[4], sB[4];
      for (int tq = 0; tq < 4; ++tq) {
        sA[tq] = MFMA32(kfA0, qf[tq][0], zA);
        sB[tq] = MFMA32(kfB0, qf[tq][0], zB);
      }
      for (int tq = 0; tq < 4; ++tq) {
        sA[tq] = MFMA32(kfA1, qf[tq][1], sA[tq]);
        sB[tq] = MFMA32(kfB1, qf[tq][1], sB[tq]);
      }

      // phase 2: softmax VALU (exp2 + pack only)
      f16x8 pf[4];
      for (int tq = 0; tq < 4; ++tq) {
        float pA0 = __builtin_amdgcn_exp2f(sA[tq][0]);
        float pA1 = __builtin_amdgcn_exp2f(sA[tq][1]);
        float pA2 = __builtin_amdgcn_exp2f(sA[tq][2]);
        float pA3 = __builtin_amdgcn_exp2f(sA[tq][3]);
        float pB0 = __builtin_amdgcn_exp2f(sB[tq][0]);
        float pB1 = __builtin_amdgcn_exp2f(sB[tq][1]);
        float pB2 = __builtin_amdgcn_exp2f(sB[tq][2]);
        float pB3 = __builtin_amdgcn_exp2f(sB[tq][3]);
        union PF { f16x8 v; h16x2 h[4]; } u;
        u.h[0] = __builtin_amdgcn_cvt_pkrtz(pA0, pA1);
        u.h[1] = __builtin_amdgcn_cvt_pkrtz(pA2, pA3);
        u.h[2] = __builtin_amdgcn_cvt_pkrtz(pB0, pB1);
        u.h[3] = __builtin_amdgcn_cvt_pkrtz(pB2, pB3);
        pf[tq] = u.v;
      }

      // phase 3: all PV MFMAs + ones-MFMA row-sum (20, independent accumulators)
      for (int tq = 0; tq < 4; ++tq) {
        for (int td = 0; td < 4; ++td)
          oacc[tq][td] = MFMA32(vf[td], pf[tq], oacc[tq][td]);
        lacc[tq] = MFMA32(onesf, pf[tq], lacc[tq]);
      }
    }
    __syncthreads();
  }

  // ---- combine the 2 kv-groups (additive partials; 68 floats, stride 69) ----
  float* cmb = (float*)smem;
  const int slot = qw * 64 + lane;
  if (g == 1) {
    float* dst = cmb + slot * 69;
    int i = 0;
    for (int tq = 0; tq < 4; ++tq)
      for (int td = 0; td < 4; ++td)
        for (int r = 0; r < 4; ++r) dst[i++] = oacc[tq][td][r];
    for (int tq = 0; tq < 4; ++tq) dst[64 + tq] = lacc[tq][0];
  }
  __syncthreads();
  if (g == 0) {
    const float* src = cmb + slot * 69;
    int i = 0;
    for (int tq = 0; tq < 4; ++tq)
      for (int td = 0; td < 4; ++td)
        for (int r = 0; r < 4; ++r) oacc[tq][td][r] += src[i++];

    for (int tq = 0; tq < 4; ++tq) {
      // lacc already holds the full k=32 reduce per column; no shuffles needed
      float l = lacc[tq][0] + src[64 + tq];
      float inv = 1.f / l;
      int row = b * T + q0 + qw * 64 + tq * 16 + l16;
      for (int td = 0; td < 4; ++td) {
        f16x4 o;
        for (int r = 0; r < 4; ++r) o[r] = (f16)(oacc[tq][td][r] * inv);
        *(f16x4*)(ctx + (size_t)row * H + h * HD + td * 16 + quad * 4) = o;
      }
    }
  }
}

// ---------- launch ----------

extern "C" void kernel_launch(void* const* d_in, const int* in_sizes, int n_in,
                              void* d_out, int out_size, void* d_ws, size_t ws_size,
                              hipStream_t stream) {
  const float* x  = (const float*)d_in[0];
  const int* mask = (const int*)d_in[1];
  const float* Wq = (const float*)d_in[2];
  const float* bq = (const float*)d_in[3];
  const float* Wk = (const float*)d_in[4];
  const float* bk = (const float*)d_in[5];
  const float* Wv = (const float*)d_in[6];
  const float* bv = (const float*)d_in[7];
  const float* Wo = (const float*)d_in[8];
  const float* bo = (const float*)d_in[9];
  float* out = (float*)d_out;

  char* ws = (char*)d_ws;
  f16* xh      = (f16*)(ws);                            // 8 MB
  f16* Wqkv_t  = (f16*)(ws + (8u  << 20));              // 6 MB
  f16* Wot     = (f16*)(ws + (14u << 20));              // 2 MB
  float* bqkv  = (float*)(ws + (16u << 20));            // 12 KB
  float* maskf = (float*)(ws + (16u << 20) + 65536);    // 16 KB
  f16* QK      = (f16*)(ws + (17u << 20));              // 16 MB [4096][2048]
  f16* ctx     = (f16*)(ws + (34u << 20));              // 8 MB
  f16* VTr     = (f16*)(ws + (43u << 20));              // 8 MB [B][NH][64][T]

  pack_all<<<dim3(5164), 256, 0, stream>>>(x, Wq, Wk, Wv, Wo, bq, bk, bv, mask,
                                           xh, Wqkv_t, Wot, bqkv, maskf);

  gemm_qkv<<<dim3(3 * H / 64, M / 128), 256, 0, stream>>>(
      xh, Wqkv_t, bqkv, QK, VTr);

  attn_fused<<<dim3(T / 256, NH, Bb), 512, 0, stream>>>(QK, VTr, maskf, ctx);

  gemm_out<<<dim3(H / 64, M / 128), 256, 0, stream>>>(ctx, Wot, bo, out);
}